// Round 1
// baseline (336.923 us; speedup 1.0000x reference)
//
#include <hip/hip_runtime.h>

#define NN 50000
#define NP 50048  // padded to multiple of 64
#define NE 800000
#define ET (NE + NN)
#define NB 196              // coarse buckets (dst>>8)
#define CAP 8192            // per-bucket capacity (avg 4337, +58 sigma)
#define EPB 4096            // edges per p1 block (4 per thread)
#define P1_B ((ET + EPB - 1) / EPB)   // 208
#define CONVW_B 32                    // 32768 / 1024
#define CONVX_B (NP * 32 / 1024)      // 1564 (exact)
#define FRONT_B (P1_B + CONVW_B + CONVX_B)
#define GEMM_B (NP / 64)              // 782
#define MID_B (NB + GEMM_B)           // 978
#define AGG1_GRP 1563                 // blocks per head; grid = 8*AGG1_GRP, bid%8 -> head -> XCD
#define AGG1_STRIDE (4 * AGG1_GRP)    // dst stride per wave (4 waves/block)

typedef __attribute__((ext_vector_type(8))) short short8;
typedef __attribute__((ext_vector_type(4))) float f32x4;

static __device__ __forceinline__ float bf2f(unsigned short u) {
  union { unsigned int i; float f; } v; v.i = ((unsigned int)u) << 16; return v.f;
}
static __device__ __forceinline__ unsigned short f2bf(float f) {
  union { unsigned int i; float f; } v; v.f = f;
  unsigned int r = v.i + 0x7fffu + ((v.i >> 16) & 1u);
  return (unsigned short)(r >> 16);
}
static __device__ __forceinline__ float lrelu(float z) { return z > 0.f ? z : 0.2f * z; }

// ---------------- fused front (1024 thr): p1 (CSR bucket, 4 edges/thread) | conv_w | conv_x ----------------
__global__ __launch_bounds__(1024) void k_front(
    const int* __restrict__ ei, int* __restrict__ gcount, int* __restrict__ tmp,
    const float* __restrict__ W1, unsigned short* __restrict__ wh,
    const float* __restrict__ x, unsigned short* __restrict__ xh) {
  __shared__ int hist[NB];
  __shared__ int lbase[NB];
  const int b = blockIdx.x;
  const int tid = threadIdx.x;
  if (b < P1_B) {
    if (tid < NB) hist[tid] = 0;
    __syncthreads();
    const int e0 = b * EPB + tid;
    int bkv[4], locv[4], pkv[4];
    bool val[4];
#pragma unroll
    for (int j = 0; j < 4; ++j) {
      int e = e0 + j * 1024;
      val[j] = (e < ET);
      int s = 0, d = 0;
      if (val[j]) {
        s = (e < NE) ? ei[e] : (e - NE);
        d = (e < NE) ? ei[NE + e] : (e - NE);
      }
      bkv[j] = d >> 8;
      pkv[j] = (s << 8) | (d & 255);
      locv[j] = val[j] ? atomicAdd(&hist[bkv[j]], 1) : 0;  // LDS atomic
    }
    __syncthreads();
    if (tid < NB) {
      int c = hist[tid];
      lbase[tid] = (c > 0) ? atomicAdd(&gcount[tid], c) : 0;
    }
    __syncthreads();
#pragma unroll
    for (int j = 0; j < 4; ++j)
      if (val[j]) tmp[bkv[j] * CAP + lbase[bkv[j]] + locv[j]] = pkv[j];
  } else if (b < P1_B + CONVW_B) {
    int i = (b - P1_B) * 1024 + tid;  // i < 32768
    int k = i >> 8, n = i & 255;
    wh[n * 128 + k] = f2bf(W1[i]);
  } else {
    int i4 = (b - P1_B - CONVW_B) * 1024 + tid;  // i4 < NP*32 exactly
    int i = i4 * 4;
    int row = i >> 7;
    float4 v = (row < NN) ? *(const float4*)(x + i) : (float4){0.f, 0.f, 0.f, 0.f};
    ushort4 h;
    h.x = f2bf(v.x);
    h.y = f2bf(v.y);
    h.z = f2bf(v.z);
    h.w = f2bf(v.w);
    *(ushort4*)(xh + i) = h;
  }
}

// ---------------- fused mid (256 thr): p2 (counting sort) | gemm1 (bf16 MFMA) ----------------
// h1 now stored HEAD-MAJOR: h1h[head][node][32] bf16 (3.2 MB per head -> fits one XCD L2).
// as1/ad1 stored head-major [head][node].
__global__ __launch_bounds__(256) void k_mid(
    const int* __restrict__ tmp, const int* __restrict__ gcount,
    int* __restrict__ ssrc, int* __restrict__ row_ptr,
    const unsigned short* __restrict__ xh, const unsigned short* __restrict__ wh,
    const float* __restrict__ a1s, const float* __restrict__ a1d,
    unsigned short* __restrict__ h1, float* __restrict__ as1, float* __restrict__ ad1) {
  __shared__ unsigned short hst[64][264];  // 33792 B; p2 path aliases into it
  const int tid = threadIdx.x;
  if (blockIdx.x < NB) {
    int* hist = (int*)&hst[0][0];
    int* sa = hist + 256;
    int* sb = sa + 256;
    int* cur = sb + 256;
    int* base_sh = cur + 256;
    const int t = tid;
    const int b = blockIdx.x;
    const int n_b = gcount[b];
    sa[t] = (t < NB) ? gcount[t] : 0;
    __syncthreads();
    {
      int* s = sa;
      int* d = sb;
      for (int off = 1; off < 256; off <<= 1) {
        int v = s[t];
        if (t >= off) v += s[t - off];
        d[t] = v;
        int* tm = s; s = d; d = tm;
        __syncthreads();
      }
      if (t == 0) {
        base_sh[0] = (b == 0) ? 0 : s[b - 1];
        if (b == 0) row_ptr[NN] = ET;
      }
    }
    hist[t] = 0;
    __syncthreads();
    const int base = base_sh[0];
    for (int i = t; i < n_b; i += 256) {
      int p = tmp[b * CAP + i];
      atomicAdd(&hist[p & 255], 1);
    }
    __syncthreads();
    sa[t] = hist[t];
    __syncthreads();
    {
      int* s = sa;
      int* d = sb;
      for (int off = 1; off < 256; off <<= 1) {
        int v = s[t];
        if (t >= off) v += s[t - off];
        d[t] = v;
        int* tm = s; s = d; d = tm;
        __syncthreads();
      }
      int excl = (t == 0) ? 0 : s[t - 1];
      int start = base + excl;
      cur[t] = start;
      int d_glob = (b << 8) + t;
      if (d_glob < NN) row_ptr[d_glob] = start;
    }
    __syncthreads();
    for (int i = t; i < n_b; i += 256) {
      int p = tmp[b * CAP + i];
      int pos = atomicAdd(&cur[p & 255], 1);  // LDS cursor
      ssrc[pos] = p >> 8;
    }
    return;
  }
  // ---- gemm1: single-pass bf16 MFMA ----
  const int gb = blockIdx.x - NB;
  const int w = tid >> 6, lane = tid & 63;
  const int quad = lane >> 4, m16 = lane & 15;
  const int row0 = gb * 64;
  const int koff = quad * 8;

  f32x4 acc[4][4];
  for (int mt = 0; mt < 4; ++mt)
    for (int nt = 0; nt < 4; ++nt) acc[mt][nt] = (f32x4){0.f, 0.f, 0.f, 0.f};

  for (int kt = 0; kt < 4; ++kt) {
    short8 ah[4], bh[4];
    for (int mt = 0; mt < 4; ++mt) {
      size_t ra = (size_t)(row0 + mt * 16 + m16) * 128 + kt * 32 + koff;
      ah[mt] = *(const short8*)(xh + ra);
    }
    for (int nt = 0; nt < 4; ++nt) {
      size_t rb = (size_t)(w * 64 + nt * 16 + m16) * 128 + kt * 32 + koff;
      bh[nt] = *(const short8*)(wh + rb);
    }
    for (int mt = 0; mt < 4; ++mt)
      for (int nt = 0; nt < 4; ++nt)
        acc[mt][nt] = __builtin_amdgcn_mfma_f32_16x16x32_bf16(ah[mt], bh[nt], acc[mt][nt], 0, 0, 0);
  }
  for (int mt = 0; mt < 4; ++mt)
    for (int nt = 0; nt < 4; ++nt) {
      int c = w * 64 + nt * 16 + m16;
      int rb = mt * 16 + quad * 4;
      for (int r = 0; r < 4; ++r) hst[rb + r][c] = f2bf(acc[mt][nt][r]);
    }
  __syncthreads();
  for (int p = 0; p < 8; ++p) {
    int idx = p * 256 + tid;
    int row = idx >> 5, u4 = idx & 31;
    int grow = row0 + row;
    if (grow < NN) {
      uint4 v = *(const uint4*)&hst[row][u4 * 8];
      int head = u4 >> 2, cg = u4 & 3;  // col = u4*8; head = col>>5; in-head col = (u4&3)*8
      *(uint4*)(h1 + ((size_t)head * NN + grow) * 32 + cg * 8) = v;
    }
  }
  for (int p = 0; p < 2; ++p) {
    int id = p * 256 + tid;
    int row = id >> 3, head = id & 7;
    int grow = row0 + row;
    if (grow < NN) {
      float sa = 0.f, sd = 0.f;
      for (int c = 0; c < 32; ++c) {
        float hv = bf2f(hst[row][head * 32 + c]);
        sa = fmaf(hv, a1s[head * 32 + c], sa);
        sd = fmaf(hv, a1d[head * 32 + c], sd);
      }
      as1[(size_t)head * NN + grow] = sa;
      ad1[(size_t)head * NN + grow] = sd;
    }
  }
}

// ---------------- Layer-1 aggregation: head-per-XCD partitioned ----------------
// head = blockIdx.x & 7  -> round-robin dispatch pins head h's gathers to XCD h.
// Per-XCD gather table = 3.2 MB (L2-resident). Wave = 1 dst: 8 edge-slots x 8 ch-lanes,
// each lane loads uint2 (4 bf16) -> full 64 B head-row per edge, no shfl broadcast chain.
// Per-head ELU+W2 partials accumulated into nd (float2) via atomicAdd.
__global__ __launch_bounds__(256) void k_agg1(
    const int* __restrict__ row_ptr, const int* __restrict__ ssrc,
    const unsigned short* __restrict__ h1h, const float* __restrict__ as1h,
    const float* __restrict__ ad1h, const float* __restrict__ b1,
    const float* __restrict__ W2, float* __restrict__ ndf) {
  const int head = blockIdx.x & 7;
  const int grp = blockIdx.x >> 3;          // 0..AGG1_GRP-1
  const int wid = threadIdx.x >> 6;
  const int lane = threadIdx.x & 63;
  const int slot = lane >> 3;               // edge slot 0..7
  const int c8 = lane & 7;                  // channel group: 4 bf16 = 8 B

  const unsigned short* __restrict__ ht = h1h + (size_t)head * NN * 32;
  const float* __restrict__ ast = as1h + (size_t)head * NN;
  const float* __restrict__ adt = ad1h + (size_t)head * NN;

  // hoist per-lane epilogue constants (channels head*32 + c8*4 + j)
  float b1c[4], w20[4], w21[4];
#pragma unroll
  for (int j = 0; j < 4; ++j) {
    int ch = head * 32 + c8 * 4 + j;
    b1c[j] = b1[ch];
    w20[j] = W2[ch * 2 + 0];
    w21[j] = W2[ch * 2 + 1];
  }

  for (int dst = grp * 4 + wid; dst < NN; dst += AGG1_STRIDE) {
    const int start = row_ptr[dst], end = row_ptr[dst + 1];
    const float adh = adt[dst];
    float s_loc = 0.f;
    float a0 = 0.f, a1 = 0.f, a2 = 0.f, a3 = 0.f;
    for (int base = start; base < end; base += 8) {
      int e = base + slot;
      bool v = e < end;
      int s = v ? ssrc[e] : 0;
      float w = 0.f;
      if (v) w = __expf(lrelu(ast[s] + adh));
      s_loc += w;  // replicated across 8 ch-lanes of this slot; reduced over slots only
      uint2 u = (uint2){0u, 0u};
      if (v) u = *(const uint2*)(ht + (size_t)s * 32 + c8 * 4);
      a0 = fmaf(w, bf2f((unsigned short)(u.x & 0xffffu)), a0);
      a1 = fmaf(w, bf2f((unsigned short)(u.x >> 16)), a1);
      a2 = fmaf(w, bf2f((unsigned short)(u.y & 0xffffu)), a2);
      a3 = fmaf(w, bf2f((unsigned short)(u.y >> 16)), a3);
    }
    // reduce across the 8 edge slots (strides 8,16,32); ch-group stays lane-local
    s_loc += __shfl_xor(s_loc, 8);
    a0 += __shfl_xor(a0, 8); a1 += __shfl_xor(a1, 8);
    a2 += __shfl_xor(a2, 8); a3 += __shfl_xor(a3, 8);
    s_loc += __shfl_xor(s_loc, 16);
    a0 += __shfl_xor(a0, 16); a1 += __shfl_xor(a1, 16);
    a2 += __shfl_xor(a2, 16); a3 += __shfl_xor(a3, 16);
    s_loc += __shfl_xor(s_loc, 32);
    a0 += __shfl_xor(a0, 32); a1 += __shfl_xor(a1, 32);
    a2 += __shfl_xor(a2, 32); a3 += __shfl_xor(a3, 32);
    const float inv_s = 1.f / (s_loc + 1e-16f);
    float av[4] = {a0, a1, a2, a3};
    float tp0 = 0.f, tp1 = 0.f;
#pragma unroll
    for (int j = 0; j < 4; ++j) {
      float vv = fmaf(av[j], inv_s, b1c[j]);
      vv = vv > 0.f ? vv : (__expf(vv) - 1.f);  // ELU
      tp0 = fmaf(vv, w20[j], tp0);
      tp1 = fmaf(vv, w21[j], tp1);
    }
    // reduce across the 8 channel groups (strides 1,2,4)
    tp0 += __shfl_xor(tp0, 1); tp1 += __shfl_xor(tp1, 1);
    tp0 += __shfl_xor(tp0, 2); tp1 += __shfl_xor(tp1, 2);
    tp0 += __shfl_xor(tp0, 4); tp1 += __shfl_xor(tp1, 4);
    if (lane == 0) {
      atomicAdd(ndf + (size_t)dst * 2 + 0, tp0);
      atomicAdd(ndf + (size_t)dst * 2 + 1, tp1);
    }
  }
}

// ---------------- Layer-2 aggregation: 8 lanes per dst; nd is float2 (tp0,tp1) ----------------
__global__ __launch_bounds__(256) void k_agg2(
    const int* __restrict__ row_ptr, const int* __restrict__ ssrc,
    const float2* __restrict__ nd, const float* __restrict__ a2s,
    const float* __restrict__ a2d, const float* __restrict__ b2,
    float* __restrict__ out) {
  int gid = blockIdx.x * 256 + threadIdx.x;
  int n = gid >> 3;
  int l8 = threadIdx.x & 7;
  if (n >= NN) return;
  int st = row_ptr[n], en = row_ptr[n + 1];
  float2 td = nd[n];
  const float s0 = a2s[0], s1 = a2s[1];
  float dv = td.x * a2d[0] + td.y * a2d[1];
  float ssum = 0.f, o0 = 0.f, o1 = 0.f;
  for (int e = st + l8; e < en; e += 8) {
    int s = ssrc[e];
    float2 v = nd[s];
    float zv = fmaf(v.x, s0, v.y * s1);
    float w = __expf(lrelu(zv + dv));
    ssum += w;
    o0 = fmaf(w, v.x, o0);
    o1 = fmaf(w, v.y, o1);
  }
  ssum += __shfl_xor(ssum, 1); o0 += __shfl_xor(o0, 1); o1 += __shfl_xor(o1, 1);
  ssum += __shfl_xor(ssum, 2); o0 += __shfl_xor(o0, 2); o1 += __shfl_xor(o1, 2);
  ssum += __shfl_xor(ssum, 4); o0 += __shfl_xor(o0, 4); o1 += __shfl_xor(o1, 4);
  if (l8 == 0) {
    float inv = 1.f / (ssum + 1e-16f);
    out[(size_t)n * 2 + 0] = o0 * inv + b2[0];
    out[(size_t)n * 2 + 1] = o1 * inv + b2[1];
  }
}

extern "C" void kernel_launch(void* const* d_in, const int* in_sizes, int n_in,
                              void* d_out, int out_size, void* d_ws, size_t ws_size,
                              hipStream_t stream) {
  const float* x = (const float*)d_in[0];
  const int* ei = (const int*)d_in[1];
  // d_in[2] = batch (unused)
  const float* W1 = (const float*)d_in[3];
  const float* a1s = (const float*)d_in[4];
  const float* a1d = (const float*)d_in[5];
  const float* b1 = (const float*)d_in[6];
  const float* W2 = (const float*)d_in[7];
  const float* a2s = (const float*)d_in[8];
  const float* a2d = (const float*)d_in[9];
  const float* b2 = (const float*)d_in[10];
  float* out = (float*)d_out;

  char* ws = (char*)d_ws;
  size_t off = 0;
  auto alloc = [&](size_t bytes) -> void* {
    void* p = ws + off;
    off += (bytes + 255) & ~(size_t)255;
    return p;
  };
  int* gcount = (int*)alloc((size_t)NB * 4);
  int* tmp = (int*)alloc((size_t)NB * CAP * 4);
  int* row_ptr = (int*)alloc((size_t)(NN + 1) * 4);
  int* ssrc = (int*)alloc((size_t)ET * 4);
  unsigned short* xh = (unsigned short*)alloc((size_t)NP * 128 * 2);
  unsigned short* wh = (unsigned short*)alloc((size_t)32768 * 2);
  unsigned short* h1 = (unsigned short*)alloc((size_t)NN * 256 * 2);  // head-major [8][NN][32]
  float* as1 = (float*)alloc((size_t)NN * 8 * 4);                     // head-major [8][NN]
  float* ad1 = (float*)alloc((size_t)NN * 8 * 4);                     // head-major [8][NN]
  float* ndf = (float*)alloc((size_t)NN * 8);                         // float2 per node (tp0,tp1)
  (void)ws_size; (void)in_sizes; (void)n_in; (void)out_size;

  hipMemsetAsync(gcount, 0, (size_t)NB * 4, stream);
  hipMemsetAsync(ndf, 0, (size_t)NN * 8, stream);
  k_front<<<FRONT_B, 1024, 0, stream>>>(ei, gcount, tmp, W1, wh, x, xh);
  k_mid<<<MID_B, 256, 0, stream>>>(tmp, gcount, ssrc, row_ptr, xh, wh, a1s, a1d, h1, as1, ad1);
  k_agg1<<<8 * AGG1_GRP, 256, 0, stream>>>(row_ptr, ssrc, h1, as1, ad1, b1, W2, ndf);
  k_agg2<<<(NN * 8 + 255) / 256, 256, 0, stream>>>(row_ptr, ssrc, (const float2*)ndf, a2s, a2d, b2, out);
}

// Round 2
// 225.908 us; speedup vs baseline: 1.4914x; 1.4914x over previous
//
#include <hip/hip_runtime.h>

#define NN 50000
#define NP 50048  // padded to multiple of 64
#define NE 800000
#define ET (NE + NN)
#define NB 196              // coarse buckets (dst>>8)
#define CAP 8192            // per-bucket capacity (avg 4337, +58 sigma)
#define EPB 4096            // edges per p1 block (4 per thread)
#define P1_B ((ET + EPB - 1) / EPB)   // 208
#define CONVW_B 32                    // 32768 / 1024
#define CONVX_B (NP * 32 / 1024)      // 1564 (exact)
#define FRONT_B (P1_B + CONVW_B + CONVX_B)
#define GEMM_B (NP / 64)              // 782
#define MID_B (NB + GEMM_B)           // 978
#define AGG1_GRP 1563                 // blocks per head (32 dst/block); grid = 8*AGG1_GRP, bid&7 -> head -> XCD

typedef __attribute__((ext_vector_type(8))) short short8;
typedef __attribute__((ext_vector_type(4))) float f32x4;

static __device__ __forceinline__ float bf2f(unsigned short u) {
  union { unsigned int i; float f; } v; v.i = ((unsigned int)u) << 16; return v.f;
}
static __device__ __forceinline__ unsigned short f2bf(float f) {
  union { unsigned int i; float f; } v; v.f = f;
  unsigned int r = v.i + 0x7fffu + ((v.i >> 16) & 1u);
  return (unsigned short)(r >> 16);
}
static __device__ __forceinline__ float lrelu(float z) { return z > 0.f ? z : 0.2f * z; }

// ---------------- fused front (1024 thr): p1 (CSR bucket, 4 edges/thread) | conv_w | conv_x ----------------
__global__ __launch_bounds__(1024) void k_front(
    const int* __restrict__ ei, int* __restrict__ gcount, int* __restrict__ tmp,
    const float* __restrict__ W1, unsigned short* __restrict__ wh,
    const float* __restrict__ x, unsigned short* __restrict__ xh) {
  __shared__ int hist[NB];
  __shared__ int lbase[NB];
  const int b = blockIdx.x;
  const int tid = threadIdx.x;
  if (b < P1_B) {
    if (tid < NB) hist[tid] = 0;
    __syncthreads();
    const int e0 = b * EPB + tid;
    int bkv[4], locv[4], pkv[4];
    bool val[4];
#pragma unroll
    for (int j = 0; j < 4; ++j) {
      int e = e0 + j * 1024;
      val[j] = (e < ET);
      int s = 0, d = 0;
      if (val[j]) {
        s = (e < NE) ? ei[e] : (e - NE);
        d = (e < NE) ? ei[NE + e] : (e - NE);
      }
      bkv[j] = d >> 8;
      pkv[j] = (s << 8) | (d & 255);
      locv[j] = val[j] ? atomicAdd(&hist[bkv[j]], 1) : 0;  // LDS atomic
    }
    __syncthreads();
    if (tid < NB) {
      int c = hist[tid];
      lbase[tid] = (c > 0) ? atomicAdd(&gcount[tid], c) : 0;
    }
    __syncthreads();
#pragma unroll
    for (int j = 0; j < 4; ++j)
      if (val[j]) tmp[bkv[j] * CAP + lbase[bkv[j]] + locv[j]] = pkv[j];
  } else if (b < P1_B + CONVW_B) {
    int i = (b - P1_B) * 1024 + tid;  // i < 32768
    int k = i >> 8, n = i & 255;
    wh[n * 128 + k] = f2bf(W1[i]);
  } else {
    int i4 = (b - P1_B - CONVW_B) * 1024 + tid;  // i4 < NP*32 exactly
    int i = i4 * 4;
    int row = i >> 7;
    float4 v = (row < NN) ? *(const float4*)(x + i) : (float4){0.f, 0.f, 0.f, 0.f};
    ushort4 h;
    h.x = f2bf(v.x);
    h.y = f2bf(v.y);
    h.z = f2bf(v.z);
    h.w = f2bf(v.w);
    *(ushort4*)(xh + i) = h;
  }
}

// ---------------- fused mid (256 thr): p2 (counting sort) | gemm1 (bf16 MFMA) ----------------
// h1 stored HEAD-MAJOR: h1h[head][node][32] bf16 (3.2 MB per head -> fits one XCD L2).
// as1/ad1 stored head-major [head][node].
__global__ __launch_bounds__(256) void k_mid(
    const int* __restrict__ tmp, const int* __restrict__ gcount,
    int* __restrict__ ssrc, int* __restrict__ row_ptr,
    const unsigned short* __restrict__ xh, const unsigned short* __restrict__ wh,
    const float* __restrict__ a1s, const float* __restrict__ a1d,
    unsigned short* __restrict__ h1, float* __restrict__ as1, float* __restrict__ ad1) {
  __shared__ unsigned short hst[64][264];  // 33792 B; p2 path aliases into it
  const int tid = threadIdx.x;
  if (blockIdx.x < NB) {
    int* hist = (int*)&hst[0][0];
    int* sa = hist + 256;
    int* sb = sa + 256;
    int* cur = sb + 256;
    int* base_sh = cur + 256;
    const int t = tid;
    const int b = blockIdx.x;
    const int n_b = gcount[b];
    sa[t] = (t < NB) ? gcount[t] : 0;
    __syncthreads();
    {
      int* s = sa;
      int* d = sb;
      for (int off = 1; off < 256; off <<= 1) {
        int v = s[t];
        if (t >= off) v += s[t - off];
        d[t] = v;
        int* tm = s; s = d; d = tm;
        __syncthreads();
      }
      if (t == 0) {
        base_sh[0] = (b == 0) ? 0 : s[b - 1];
        if (b == 0) row_ptr[NN] = ET;
      }
    }
    hist[t] = 0;
    __syncthreads();
    const int base = base_sh[0];
    for (int i = t; i < n_b; i += 256) {
      int p = tmp[b * CAP + i];
      atomicAdd(&hist[p & 255], 1);
    }
    __syncthreads();
    sa[t] = hist[t];
    __syncthreads();
    {
      int* s = sa;
      int* d = sb;
      for (int off = 1; off < 256; off <<= 1) {
        int v = s[t];
        if (t >= off) v += s[t - off];
        d[t] = v;
        int* tm = s; s = d; d = tm;
        __syncthreads();
      }
      int excl = (t == 0) ? 0 : s[t - 1];
      int start = base + excl;
      cur[t] = start;
      int d_glob = (b << 8) + t;
      if (d_glob < NN) row_ptr[d_glob] = start;
    }
    __syncthreads();
    for (int i = t; i < n_b; i += 256) {
      int p = tmp[b * CAP + i];
      int pos = atomicAdd(&cur[p & 255], 1);  // LDS cursor
      ssrc[pos] = p >> 8;
    }
    return;
  }
  // ---- gemm1: single-pass bf16 MFMA ----
  const int gb = blockIdx.x - NB;
  const int w = tid >> 6, lane = tid & 63;
  const int quad = lane >> 4, m16 = lane & 15;
  const int row0 = gb * 64;
  const int koff = quad * 8;

  f32x4 acc[4][4];
  for (int mt = 0; mt < 4; ++mt)
    for (int nt = 0; nt < 4; ++nt) acc[mt][nt] = (f32x4){0.f, 0.f, 0.f, 0.f};

  for (int kt = 0; kt < 4; ++kt) {
    short8 ah[4], bh[4];
    for (int mt = 0; mt < 4; ++mt) {
      size_t ra = (size_t)(row0 + mt * 16 + m16) * 128 + kt * 32 + koff;
      ah[mt] = *(const short8*)(xh + ra);
    }
    for (int nt = 0; nt < 4; ++nt) {
      size_t rb = (size_t)(w * 64 + nt * 16 + m16) * 128 + kt * 32 + koff;
      bh[nt] = *(const short8*)(wh + rb);
    }
    for (int mt = 0; mt < 4; ++mt)
      for (int nt = 0; nt < 4; ++nt)
        acc[mt][nt] = __builtin_amdgcn_mfma_f32_16x16x32_bf16(ah[mt], bh[nt], acc[mt][nt], 0, 0, 0);
  }
  for (int mt = 0; mt < 4; ++mt)
    for (int nt = 0; nt < 4; ++nt) {
      int c = w * 64 + nt * 16 + m16;
      int rb = mt * 16 + quad * 4;
      for (int r = 0; r < 4; ++r) hst[rb + r][c] = f2bf(acc[mt][nt][r]);
    }
  __syncthreads();
  for (int p = 0; p < 8; ++p) {
    int idx = p * 256 + tid;
    int row = idx >> 5, u4 = idx & 31;
    int grow = row0 + row;
    if (grow < NN) {
      uint4 v = *(const uint4*)&hst[row][u4 * 8];
      int head = u4 >> 2, cg = u4 & 3;  // col = u4*8; head = col>>5; in-head col = (u4&3)*8
      *(uint4*)(h1 + ((size_t)head * NN + grow) * 32 + cg * 8) = v;
    }
  }
  for (int p = 0; p < 2; ++p) {
    int id = p * 256 + tid;
    int row = id >> 3, head = id & 7;
    int grow = row0 + row;
    if (grow < NN) {
      float sa = 0.f, sd = 0.f;
      for (int c = 0; c < 32; ++c) {
        float hv = bf2f(hst[row][head * 32 + c]);
        sa = fmaf(hv, a1s[head * 32 + c], sa);
        sd = fmaf(hv, a1d[head * 32 + c], sd);
      }
      as1[(size_t)head * NN + grow] = sa;
      ad1[(size_t)head * NN + grow] = sd;
    }
  }
}

// ---------------- Layer-1 aggregation: head-per-XCD, lane-per-edge, 8 lanes per (dst,head) ----------------
// head = blockIdx.x & 7 -> round-robin dispatch pins head h's gathers to XCD h (proven: FETCH 220->31 MB).
// Each lane owns whole edges: 1 ssrc load, 1 exp (no redundancy), full 64 B head-row via 4x uint4
// (loads 2-4 hit L1; L2 sees exactly 64 B/edge). 32-float per-lane acc; 8-lane fold reduction
// (28 shfls, statically indexed) leaves lane l8 holding channels chbase..chbase+3 (permuted mapping
// absorbed into hoisted b1/W2 constants). Per-head ELU+W2 partials combined via 2 atomicAdds.
__global__ __launch_bounds__(256) void k_agg1(
    const int* __restrict__ row_ptr, const int* __restrict__ ssrc,
    const unsigned short* __restrict__ h1h, const float* __restrict__ as1h,
    const float* __restrict__ ad1h, const float* __restrict__ b1,
    const float* __restrict__ W2, float* __restrict__ ndf) {
  const int head = blockIdx.x & 7;
  const int gb = blockIdx.x >> 3;           // 0..AGG1_GRP-1
  const int l8 = threadIdx.x & 7;
  const int dst = gb * 32 + (threadIdx.x >> 3);
  if (dst >= NN) return;                    // whole 8-lane group exits together

  const unsigned short* __restrict__ ht = h1h + (size_t)head * NN * 32;
  const float* __restrict__ ast = as1h + (size_t)head * NN;

  const int b0 = l8 & 1, b1_ = (l8 >> 1) & 1, b2 = (l8 >> 2) & 1;
  const int chbase = 16 * b0 + 8 * b1_ + 4 * b2;  // fold-reduction output channel block

  float b1c[4], w20[4], w21[4];
#pragma unroll
  for (int j = 0; j < 4; ++j) {
    int ch = head * 32 + chbase + j;
    b1c[j] = b1[ch];
    w20[j] = W2[ch * 2 + 0];
    w21[j] = W2[ch * 2 + 1];
  }

  const int start = row_ptr[dst], end = row_ptr[dst + 1];
  const float adh = ad1h[(size_t)head * NN + dst];

  float acc[32];
#pragma unroll
  for (int i = 0; i < 32; ++i) acc[i] = 0.f;
  float wsum = 0.f;

  for (int e0 = start; e0 < end; e0 += 8) {
    int e = e0 + l8;
    bool v = e < end;
    int s = v ? ssrc[e] : 0;
    float w = 0.f;
    if (v) w = __expf(lrelu(ast[s] + adh));
    wsum += w;
    const uint4* rp = (const uint4*)(ht + (size_t)s * 32);
    uint4 q0 = rp[0], q1 = rp[1], q2 = rp[2], q3 = rp[3];
    unsigned int uu[16] = {q0.x, q0.y, q0.z, q0.w, q1.x, q1.y, q1.z, q1.w,
                           q2.x, q2.y, q2.z, q2.w, q3.x, q3.y, q3.z, q3.w};
#pragma unroll
    for (int i = 0; i < 16; ++i) {
      acc[2 * i] = fmaf(w, bf2f((unsigned short)(uu[i] & 0xffffu)), acc[2 * i]);
      acc[2 * i + 1] = fmaf(w, bf2f((unsigned short)(uu[i] >> 16)), acc[2 * i + 1]);
    }
  }

  // fold reduction across the 8 lanes of the group (xor 1,2,4) -> lane holds 4 channels
  float na[16];
#pragma unroll
  for (int i = 0; i < 16; ++i) {
    float send = b0 ? acc[i] : acc[i + 16];
    float keep = b0 ? acc[i + 16] : acc[i];
    na[i] = keep + __shfl_xor(send, 1);
  }
  float nb[8];
#pragma unroll
  for (int i = 0; i < 8; ++i) {
    float send = b1_ ? na[i] : na[i + 8];
    float keep = b1_ ? na[i + 8] : na[i];
    nb[i] = keep + __shfl_xor(send, 2);
  }
  float nc[4];
#pragma unroll
  for (int i = 0; i < 4; ++i) {
    float send = b2 ? nb[i] : nb[i + 4];
    float keep = b2 ? nb[i + 4] : nb[i];
    nc[i] = keep + __shfl_xor(send, 4);
  }

  wsum += __shfl_xor(wsum, 1);
  wsum += __shfl_xor(wsum, 2);
  wsum += __shfl_xor(wsum, 4);
  const float inv_s = 1.f / (wsum + 1e-16f);

  float tp0 = 0.f, tp1 = 0.f;
#pragma unroll
  for (int j = 0; j < 4; ++j) {
    float vv = fmaf(nc[j], inv_s, b1c[j]);
    vv = vv > 0.f ? vv : (__expf(vv) - 1.f);  // ELU
    tp0 = fmaf(vv, w20[j], tp0);
    tp1 = fmaf(vv, w21[j], tp1);
  }
  tp0 += __shfl_xor(tp0, 1); tp1 += __shfl_xor(tp1, 1);
  tp0 += __shfl_xor(tp0, 2); tp1 += __shfl_xor(tp1, 2);
  tp0 += __shfl_xor(tp0, 4); tp1 += __shfl_xor(tp1, 4);
  if (l8 == 0) {
    atomicAdd(ndf + (size_t)dst * 2 + 0, tp0);
    atomicAdd(ndf + (size_t)dst * 2 + 1, tp1);
  }
}

// ---------------- Layer-2 aggregation: 8 lanes per dst; nd is float2 (tp0,tp1) ----------------
__global__ __launch_bounds__(256) void k_agg2(
    const int* __restrict__ row_ptr, const int* __restrict__ ssrc,
    const float2* __restrict__ nd, const float* __restrict__ a2s,
    const float* __restrict__ a2d, const float* __restrict__ b2,
    float* __restrict__ out) {
  int gid = blockIdx.x * 256 + threadIdx.x;
  int n = gid >> 3;
  int l8 = threadIdx.x & 7;
  if (n >= NN) return;
  int st = row_ptr[n], en = row_ptr[n + 1];
  float2 td = nd[n];
  const float s0 = a2s[0], s1 = a2s[1];
  float dv = td.x * a2d[0] + td.y * a2d[1];
  float ssum = 0.f, o0 = 0.f, o1 = 0.f;
  for (int e = st + l8; e < en; e += 8) {
    int s = ssrc[e];
    float2 v = nd[s];
    float zv = fmaf(v.x, s0, v.y * s1);
    float w = __expf(lrelu(zv + dv));
    ssum += w;
    o0 = fmaf(w, v.x, o0);
    o1 = fmaf(w, v.y, o1);
  }
  ssum += __shfl_xor(ssum, 1); o0 += __shfl_xor(o0, 1); o1 += __shfl_xor(o1, 1);
  ssum += __shfl_xor(ssum, 2); o0 += __shfl_xor(o0, 2); o1 += __shfl_xor(o1, 2);
  ssum += __shfl_xor(ssum, 4); o0 += __shfl_xor(o0, 4); o1 += __shfl_xor(o1, 4);
  if (l8 == 0) {
    float inv = 1.f / (ssum + 1e-16f);
    out[(size_t)n * 2 + 0] = o0 * inv + b2[0];
    out[(size_t)n * 2 + 1] = o1 * inv + b2[1];
  }
}

extern "C" void kernel_launch(void* const* d_in, const int* in_sizes, int n_in,
                              void* d_out, int out_size, void* d_ws, size_t ws_size,
                              hipStream_t stream) {
  const float* x = (const float*)d_in[0];
  const int* ei = (const int*)d_in[1];
  // d_in[2] = batch (unused)
  const float* W1 = (const float*)d_in[3];
  const float* a1s = (const float*)d_in[4];
  const float* a1d = (const float*)d_in[5];
  const float* b1 = (const float*)d_in[6];
  const float* W2 = (const float*)d_in[7];
  const float* a2s = (const float*)d_in[8];
  const float* a2d = (const float*)d_in[9];
  const float* b2 = (const float*)d_in[10];
  float* out = (float*)d_out;

  char* ws = (char*)d_ws;
  size_t off = 0;
  auto alloc = [&](size_t bytes) -> void* {
    void* p = ws + off;
    off += (bytes + 255) & ~(size_t)255;
    return p;
  };
  int* gcount = (int*)alloc((size_t)NB * 4);
  int* tmp = (int*)alloc((size_t)NB * CAP * 4);
  int* row_ptr = (int*)alloc((size_t)(NN + 1) * 4);
  int* ssrc = (int*)alloc((size_t)ET * 4);
  unsigned short* xh = (unsigned short*)alloc((size_t)NP * 128 * 2);
  unsigned short* wh = (unsigned short*)alloc((size_t)32768 * 2);
  unsigned short* h1 = (unsigned short*)alloc((size_t)NN * 256 * 2);  // head-major [8][NN][32]
  float* as1 = (float*)alloc((size_t)NN * 8 * 4);                     // head-major [8][NN]
  float* ad1 = (float*)alloc((size_t)NN * 8 * 4);                     // head-major [8][NN]
  float* ndf = (float*)alloc((size_t)NN * 8);                         // float2 per node (tp0,tp1)
  (void)ws_size; (void)in_sizes; (void)n_in; (void)out_size;

  hipMemsetAsync(gcount, 0, (size_t)NB * 4, stream);
  hipMemsetAsync(ndf, 0, (size_t)NN * 8, stream);
  k_front<<<FRONT_B, 1024, 0, stream>>>(ei, gcount, tmp, W1, wh, x, xh);
  k_mid<<<MID_B, 256, 0, stream>>>(tmp, gcount, ssrc, row_ptr, xh, wh, a1s, a1d, h1, as1, ad1);
  k_agg1<<<8 * AGG1_GRP, 256, 0, stream>>>(row_ptr, ssrc, h1, as1, ad1, b1, W2, ndf);
  k_agg2<<<(NN * 8 + 255) / 256, 256, 0, stream>>>(row_ptr, ssrc, (const float2*)ndf, a2s, a2d, b2, out);
}

// Round 3
// 224.264 us; speedup vs baseline: 1.5023x; 1.0073x over previous
//
#include <hip/hip_runtime.h>

#define NN 50000
#define NP 50048  // padded to multiple of 64
#define NE 800000
#define ET (NE + NN)
#define NB 196              // coarse buckets (dst>>8)
#define CAP 8192            // per-bucket capacity (avg 4337, +58 sigma)
#define EPB 4096            // edges per p1 block (4 per thread)
#define P1_B ((ET + EPB - 1) / EPB)   // 208
#define CONVW_B 32                    // 32768 / 1024
#define CONVX_B (NP * 32 / 1024)      // 1564 (exact)
#define FRONT_B (P1_B + CONVW_B + CONVX_B)
#define GEMM_B (NP / 64)              // 782
#define MID_B (NB + GEMM_B)           // 978
#define AGG1_GRP 1563                 // blocks per head (32 dst/block); grid = 8*AGG1_GRP, bid&7 -> head -> XCD

typedef __attribute__((ext_vector_type(8))) short short8;
typedef __attribute__((ext_vector_type(4))) float f32x4;

static __device__ __forceinline__ float bf2f(unsigned short u) {
  union { unsigned int i; float f; } v; v.i = ((unsigned int)u) << 16; return v.f;
}
static __device__ __forceinline__ unsigned short f2bf(float f) {
  union { unsigned int i; float f; } v; v.f = f;
  unsigned int r = v.i + 0x7fffu + ((v.i >> 16) & 1u);
  return (unsigned short)(r >> 16);
}
static __device__ __forceinline__ float lrelu(float z) { return z > 0.f ? z : 0.2f * z; }

// ---------------- fused front (1024 thr): p1 (CSR bucket, 4 edges/thread) | conv_w | conv_x ----------------
__global__ __launch_bounds__(1024) void k_front(
    const int* __restrict__ ei, int* __restrict__ gcount, int* __restrict__ tmp,
    const float* __restrict__ W1, unsigned short* __restrict__ wh,
    const float* __restrict__ x, unsigned short* __restrict__ xh) {
  __shared__ int hist[NB];
  __shared__ int lbase[NB];
  const int b = blockIdx.x;
  const int tid = threadIdx.x;
  if (b < P1_B) {
    if (tid < NB) hist[tid] = 0;
    __syncthreads();
    const int e0 = b * EPB + tid;
    int bkv[4], locv[4], pkv[4];
    bool val[4];
#pragma unroll
    for (int j = 0; j < 4; ++j) {
      int e = e0 + j * 1024;
      val[j] = (e < ET);
      int s = 0, d = 0;
      if (val[j]) {
        s = (e < NE) ? ei[e] : (e - NE);
        d = (e < NE) ? ei[NE + e] : (e - NE);
      }
      bkv[j] = d >> 8;
      pkv[j] = (s << 8) | (d & 255);
      locv[j] = val[j] ? atomicAdd(&hist[bkv[j]], 1) : 0;  // LDS atomic
    }
    __syncthreads();
    if (tid < NB) {
      int c = hist[tid];
      lbase[tid] = (c > 0) ? atomicAdd(&gcount[tid], c) : 0;
    }
    __syncthreads();
#pragma unroll
    for (int j = 0; j < 4; ++j)
      if (val[j]) tmp[bkv[j] * CAP + lbase[bkv[j]] + locv[j]] = pkv[j];
  } else if (b < P1_B + CONVW_B) {
    int i = (b - P1_B) * 1024 + tid;  // i < 32768
    int k = i >> 8, n = i & 255;
    wh[n * 128 + k] = f2bf(W1[i]);
  } else {
    int i4 = (b - P1_B - CONVW_B) * 1024 + tid;  // i4 < NP*32 exactly
    int i = i4 * 4;
    int row = i >> 7;
    float4 v = (row < NN) ? *(const float4*)(x + i) : (float4){0.f, 0.f, 0.f, 0.f};
    ushort4 h;
    h.x = f2bf(v.x);
    h.y = f2bf(v.y);
    h.z = f2bf(v.z);
    h.w = f2bf(v.w);
    *(ushort4*)(xh + i) = h;
  }
}

// ---------------- fused mid (256 thr): p2 (counting sort) | gemm1 (bf16 MFMA) ----------------
// h1 stored HEAD-MAJOR: h1h[head][node][32] bf16 (3.2 MB per head -> fits one XCD L2).
// as1/ad1 stored head-major [head][node].
__global__ __launch_bounds__(256) void k_mid(
    const int* __restrict__ tmp, const int* __restrict__ gcount,
    int* __restrict__ ssrc, int* __restrict__ row_ptr,
    const unsigned short* __restrict__ xh, const unsigned short* __restrict__ wh,
    const float* __restrict__ a1s, const float* __restrict__ a1d,
    unsigned short* __restrict__ h1, float* __restrict__ as1, float* __restrict__ ad1) {
  __shared__ unsigned short hst[64][264];  // 33792 B; p2 path aliases into it
  const int tid = threadIdx.x;
  if (blockIdx.x < NB) {
    int* hist = (int*)&hst[0][0];
    int* sa = hist + 256;
    int* sb = sa + 256;
    int* cur = sb + 256;
    int* base_sh = cur + 256;
    const int t = tid;
    const int b = blockIdx.x;
    const int n_b = gcount[b];
    sa[t] = (t < NB) ? gcount[t] : 0;
    __syncthreads();
    {
      int* s = sa;
      int* d = sb;
      for (int off = 1; off < 256; off <<= 1) {
        int v = s[t];
        if (t >= off) v += s[t - off];
        d[t] = v;
        int* tm = s; s = d; d = tm;
        __syncthreads();
      }
      if (t == 0) {
        base_sh[0] = (b == 0) ? 0 : s[b - 1];
        if (b == 0) row_ptr[NN] = ET;
      }
    }
    hist[t] = 0;
    __syncthreads();
    const int base = base_sh[0];
    for (int i = t; i < n_b; i += 256) {
      int p = tmp[b * CAP + i];
      atomicAdd(&hist[p & 255], 1);
    }
    __syncthreads();
    sa[t] = hist[t];
    __syncthreads();
    {
      int* s = sa;
      int* d = sb;
      for (int off = 1; off < 256; off <<= 1) {
        int v = s[t];
        if (t >= off) v += s[t - off];
        d[t] = v;
        int* tm = s; s = d; d = tm;
        __syncthreads();
      }
      int excl = (t == 0) ? 0 : s[t - 1];
      int start = base + excl;
      cur[t] = start;
      int d_glob = (b << 8) + t;
      if (d_glob < NN) row_ptr[d_glob] = start;
    }
    __syncthreads();
    for (int i = t; i < n_b; i += 256) {
      int p = tmp[b * CAP + i];
      int pos = atomicAdd(&cur[p & 255], 1);  // LDS cursor
      ssrc[pos] = p >> 8;
    }
    return;
  }
  // ---- gemm1: single-pass bf16 MFMA ----
  const int gb = blockIdx.x - NB;
  const int w = tid >> 6, lane = tid & 63;
  const int quad = lane >> 4, m16 = lane & 15;
  const int row0 = gb * 64;
  const int koff = quad * 8;

  f32x4 acc[4][4];
  for (int mt = 0; mt < 4; ++mt)
    for (int nt = 0; nt < 4; ++nt) acc[mt][nt] = (f32x4){0.f, 0.f, 0.f, 0.f};

  for (int kt = 0; kt < 4; ++kt) {
    short8 ah[4], bh[4];
    for (int mt = 0; mt < 4; ++mt) {
      size_t ra = (size_t)(row0 + mt * 16 + m16) * 128 + kt * 32 + koff;
      ah[mt] = *(const short8*)(xh + ra);
    }
    for (int nt = 0; nt < 4; ++nt) {
      size_t rb = (size_t)(w * 64 + nt * 16 + m16) * 128 + kt * 32 + koff;
      bh[nt] = *(const short8*)(wh + rb);
    }
    for (int mt = 0; mt < 4; ++mt)
      for (int nt = 0; nt < 4; ++nt)
        acc[mt][nt] = __builtin_amdgcn_mfma_f32_16x16x32_bf16(ah[mt], bh[nt], acc[mt][nt], 0, 0, 0);
  }
  for (int mt = 0; mt < 4; ++mt)
    for (int nt = 0; nt < 4; ++nt) {
      int c = w * 64 + nt * 16 + m16;
      int rb = mt * 16 + quad * 4;
      for (int r = 0; r < 4; ++r) hst[rb + r][c] = f2bf(acc[mt][nt][r]);
    }
  __syncthreads();
  for (int p = 0; p < 8; ++p) {
    int idx = p * 256 + tid;
    int row = idx >> 5, u4 = idx & 31;
    int grow = row0 + row;
    if (grow < NN) {
      uint4 v = *(const uint4*)&hst[row][u4 * 8];
      int head = u4 >> 2, cg = u4 & 3;  // col = u4*8; head = col>>5; in-head col = (u4&3)*8
      *(uint4*)(h1 + ((size_t)head * NN + grow) * 32 + cg * 8) = v;
    }
  }
  for (int p = 0; p < 2; ++p) {
    int id = p * 256 + tid;
    int row = id >> 3, head = id & 7;
    int grow = row0 + row;
    if (grow < NN) {
      float sa = 0.f, sd = 0.f;
      for (int c = 0; c < 32; ++c) {
        float hv = bf2f(hst[row][head * 32 + c]);
        sa = fmaf(hv, a1s[head * 32 + c], sa);
        sd = fmaf(hv, a1d[head * 32 + c], sd);
      }
      as1[(size_t)head * NN + grow] = sa;
      ad1[(size_t)head * NN + grow] = sd;
    }
  }
}

#define UNP(Q, B)                                                              \
  do {                                                                         \
    acc[B + 0] = fmaf(w, bf2f((unsigned short)(Q.x & 0xffffu)), acc[B + 0]);   \
    acc[B + 1] = fmaf(w, bf2f((unsigned short)(Q.x >> 16)), acc[B + 1]);       \
    acc[B + 2] = fmaf(w, bf2f((unsigned short)(Q.y & 0xffffu)), acc[B + 2]);   \
    acc[B + 3] = fmaf(w, bf2f((unsigned short)(Q.y >> 16)), acc[B + 3]);       \
    acc[B + 4] = fmaf(w, bf2f((unsigned short)(Q.z & 0xffffu)), acc[B + 4]);   \
    acc[B + 5] = fmaf(w, bf2f((unsigned short)(Q.z >> 16)), acc[B + 5]);       \
    acc[B + 6] = fmaf(w, bf2f((unsigned short)(Q.w & 0xffffu)), acc[B + 6]);   \
    acc[B + 7] = fmaf(w, bf2f((unsigned short)(Q.w >> 16)), acc[B + 7]);       \
  } while (0)

// ---------------- Layer-1 aggregation: head-per-XCD, lane-per-edge, depth-2 software pipeline ----------------
// head = blockIdx.x & 7 -> XCD pinning (proven: FETCH 220->31 MB). Lane owns whole edges (1 exp, no
// redundancy). R2 lesson: acc[32] ate the 36-VGPR allocation -> compiler serialized the 4 uint4 row
// loads into dependent L2 round trips (~1200 cy/iter). Fix: explicit depth-2 pipeline — issue batch
// n+1's loads (ssrc, as1, 4x uint4) BEFORE unpacking batch n, forcing ~16 extra load-dest VGPRs and
// overlapping L2 latency with the 64-op unpack. Fold reduction + epilogue unchanged (verified).
__global__ __launch_bounds__(256) void k_agg1(
    const int* __restrict__ row_ptr, const int* __restrict__ ssrc,
    const unsigned short* __restrict__ h1h, const float* __restrict__ as1h,
    const float* __restrict__ ad1h, const float* __restrict__ b1,
    const float* __restrict__ W2, float* __restrict__ ndf) {
  const int head = blockIdx.x & 7;
  const int gb = blockIdx.x >> 3;           // 0..AGG1_GRP-1
  const int l8 = threadIdx.x & 7;
  const int dst = gb * 32 + (threadIdx.x >> 3);
  if (dst >= NN) return;                    // whole 8-lane group exits together

  const unsigned short* __restrict__ ht = h1h + (size_t)head * NN * 32;
  const float* __restrict__ ast = as1h + (size_t)head * NN;

  const int b0 = l8 & 1, b1_ = (l8 >> 1) & 1, b2 = (l8 >> 2) & 1;
  const int chbase = 16 * b0 + 8 * b1_ + 4 * b2;  // fold-reduction output channel block

  float b1c[4], w20[4], w21[4];
#pragma unroll
  for (int j = 0; j < 4; ++j) {
    int ch = head * 32 + chbase + j;
    b1c[j] = b1[ch];
    w20[j] = W2[ch * 2 + 0];
    w21[j] = W2[ch * 2 + 1];
  }

  const int start = row_ptr[dst], end = row_ptr[dst + 1];
  const float adh = ad1h[(size_t)head * NN + dst];

  float acc[32];
#pragma unroll
  for (int i = 0; i < 32; ++i) acc[i] = 0.f;
  float wsum = 0.f;

  // ---- pipelined edge loop (deg >= 1 always: self-loops) ----
  int e = start + l8;
  bool v = e < end;
  int s = v ? ssrc[e] : 0;                  // invalid lanes read row 0 (safe, masked by w=0)
  float asv = ast[s];
  const uint4* rp = (const uint4*)(ht + (size_t)s * 32);
  uint4 q0 = rp[0], q1 = rp[1], q2 = rp[2], q3 = rp[3];

  while (v) {
    // issue next batch's loads first (independent of current unpack)
    int en = e + 8;
    bool vn = en < end;
    int sn = vn ? ssrc[en] : 0;
    float asn = ast[sn];
    const uint4* rpn = (const uint4*)(ht + (size_t)sn * 32);
    uint4 p0 = rpn[0], p1 = rpn[1], p2 = rpn[2], p3 = rpn[3];

    // consume current batch (loads already in flight since last iteration)
    float w = __expf(lrelu(asv + adh));
    wsum += w;
    UNP(q0, 0);
    UNP(q1, 8);
    UNP(q2, 16);
    UNP(q3, 24);

    e = en; v = vn; asv = asn;
    q0 = p0; q1 = p1; q2 = p2; q3 = p3;
  }

  // fold reduction across the 8 lanes of the group (xor 1,2,4) -> lane holds 4 channels
  float na[16];
#pragma unroll
  for (int i = 0; i < 16; ++i) {
    float send = b0 ? acc[i] : acc[i + 16];
    float keep = b0 ? acc[i + 16] : acc[i];
    na[i] = keep + __shfl_xor(send, 1);
  }
  float nb[8];
#pragma unroll
  for (int i = 0; i < 8; ++i) {
    float send = b1_ ? na[i] : na[i + 8];
    float keep = b1_ ? na[i + 8] : na[i];
    nb[i] = keep + __shfl_xor(send, 2);
  }
  float nc[4];
#pragma unroll
  for (int i = 0; i < 4; ++i) {
    float send = b2 ? nb[i] : nb[i + 4];
    float keep = b2 ? nb[i + 4] : nb[i];
    nc[i] = keep + __shfl_xor(send, 4);
  }

  wsum += __shfl_xor(wsum, 1);
  wsum += __shfl_xor(wsum, 2);
  wsum += __shfl_xor(wsum, 4);
  const float inv_s = 1.f / (wsum + 1e-16f);

  float tp0 = 0.f, tp1 = 0.f;
#pragma unroll
  for (int j = 0; j < 4; ++j) {
    float vv = fmaf(nc[j], inv_s, b1c[j]);
    vv = vv > 0.f ? vv : (__expf(vv) - 1.f);  // ELU
    tp0 = fmaf(vv, w20[j], tp0);
    tp1 = fmaf(vv, w21[j], tp1);
  }
  tp0 += __shfl_xor(tp0, 1); tp1 += __shfl_xor(tp1, 1);
  tp0 += __shfl_xor(tp0, 2); tp1 += __shfl_xor(tp1, 2);
  tp0 += __shfl_xor(tp0, 4); tp1 += __shfl_xor(tp1, 4);
  if (l8 == 0) {
    atomicAdd(ndf + (size_t)dst * 2 + 0, tp0);
    atomicAdd(ndf + (size_t)dst * 2 + 1, tp1);
  }
}

// ---------------- Layer-2 aggregation: 8 lanes per dst; nd is float2 (tp0,tp1) ----------------
__global__ __launch_bounds__(256) void k_agg2(
    const int* __restrict__ row_ptr, const int* __restrict__ ssrc,
    const float2* __restrict__ nd, const float* __restrict__ a2s,
    const float* __restrict__ a2d, const float* __restrict__ b2,
    float* __restrict__ out) {
  int gid = blockIdx.x * 256 + threadIdx.x;
  int n = gid >> 3;
  int l8 = threadIdx.x & 7;
  if (n >= NN) return;
  int st = row_ptr[n], en = row_ptr[n + 1];
  float2 td = nd[n];
  const float s0 = a2s[0], s1 = a2s[1];
  float dv = td.x * a2d[0] + td.y * a2d[1];
  float ssum = 0.f, o0 = 0.f, o1 = 0.f;
  for (int e = st + l8; e < en; e += 8) {
    int s = ssrc[e];
    float2 v = nd[s];
    float zv = fmaf(v.x, s0, v.y * s1);
    float w = __expf(lrelu(zv + dv));
    ssum += w;
    o0 = fmaf(w, v.x, o0);
    o1 = fmaf(w, v.y, o1);
  }
  ssum += __shfl_xor(ssum, 1); o0 += __shfl_xor(o0, 1); o1 += __shfl_xor(o1, 1);
  ssum += __shfl_xor(ssum, 2); o0 += __shfl_xor(o0, 2); o1 += __shfl_xor(o1, 2);
  ssum += __shfl_xor(ssum, 4); o0 += __shfl_xor(o0, 4); o1 += __shfl_xor(o1, 4);
  if (l8 == 0) {
    float inv = 1.f / (ssum + 1e-16f);
    out[(size_t)n * 2 + 0] = o0 * inv + b2[0];
    out[(size_t)n * 2 + 1] = o1 * inv + b2[1];
  }
}

extern "C" void kernel_launch(void* const* d_in, const int* in_sizes, int n_in,
                              void* d_out, int out_size, void* d_ws, size_t ws_size,
                              hipStream_t stream) {
  const float* x = (const float*)d_in[0];
  const int* ei = (const int*)d_in[1];
  // d_in[2] = batch (unused)
  const float* W1 = (const float*)d_in[3];
  const float* a1s = (const float*)d_in[4];
  const float* a1d = (const float*)d_in[5];
  const float* b1 = (const float*)d_in[6];
  const float* W2 = (const float*)d_in[7];
  const float* a2s = (const float*)d_in[8];
  const float* a2d = (const float*)d_in[9];
  const float* b2 = (const float*)d_in[10];
  float* out = (float*)d_out;

  char* ws = (char*)d_ws;
  size_t off = 0;
  auto alloc = [&](size_t bytes) -> void* {
    void* p = ws + off;
    off += (bytes + 255) & ~(size_t)255;
    return p;
  };
  int* gcount = (int*)alloc((size_t)NB * 4);
  int* tmp = (int*)alloc((size_t)NB * CAP * 4);
  int* row_ptr = (int*)alloc((size_t)(NN + 1) * 4);
  int* ssrc = (int*)alloc((size_t)ET * 4);
  unsigned short* xh = (unsigned short*)alloc((size_t)NP * 128 * 2);
  unsigned short* wh = (unsigned short*)alloc((size_t)32768 * 2);
  unsigned short* h1 = (unsigned short*)alloc((size_t)NN * 256 * 2);  // head-major [8][NN][32]
  float* as1 = (float*)alloc((size_t)NN * 8 * 4);                     // head-major [8][NN]
  float* ad1 = (float*)alloc((size_t)NN * 8 * 4);                     // head-major [8][NN]
  float* ndf = (float*)alloc((size_t)NN * 8);                         // float2 per node (tp0,tp1)
  (void)ws_size; (void)in_sizes; (void)n_in; (void)out_size;

  hipMemsetAsync(gcount, 0, (size_t)NB * 4, stream);
  hipMemsetAsync(ndf, 0, (size_t)NN * 8, stream);
  k_front<<<FRONT_B, 1024, 0, stream>>>(ei, gcount, tmp, W1, wh, x, xh);
  k_mid<<<MID_B, 256, 0, stream>>>(tmp, gcount, ssrc, row_ptr, xh, wh, a1s, a1d, h1, as1, ad1);
  k_agg1<<<8 * AGG1_GRP, 256, 0, stream>>>(row_ptr, ssrc, h1, as1, ad1, b1, W2, ndf);
  k_agg2<<<(NN * 8 + 255) / 256, 256, 0, stream>>>(row_ptr, ssrc, (const float2*)ndf, a2s, a2d, b2, out);
}